// Round 12
// baseline (484.965 us; speedup 1.0000x reference)
//
#include <hip/hip_runtime.h>
#include <hip/hip_bf16.h>

#define H 128

using bf16x8 = __attribute__((ext_vector_type(8))) short;
using f32x4  = __attribute__((ext_vector_type(4))) float;

__device__ inline unsigned short f2bf(float f) {
    unsigned u = __float_as_uint(f);
    unsigned r = (u + 0x7fffu + ((u >> 16) & 1u)) >> 16;
    return (unsigned short)r;
}
__device__ inline float bf2f(unsigned short b) {
    return __uint_as_float(((unsigned)b) << 16);
}

// ---------------- CSR build ----------------

__global__ void k_zero_i32(int* __restrict__ p, int n) {
    int i = blockIdx.x * blockDim.x + threadIdx.x;
    if (i < n) p[i] = 0;
}

__global__ void k_count(const int* __restrict__ dst, int* __restrict__ deg, int e) {
    int i = blockIdx.x * blockDim.x + threadIdx.x;
    if (i < e) atomicAdd(&deg[dst[i]], 1);
}

__global__ __launch_bounds__(1024) void k_scan_partial(const int* __restrict__ deg,
                                                       int* __restrict__ partials, int n) {
    __shared__ int sm[1024];
    int t = threadIdx.x;
    int i = blockIdx.x * 1024 + t;
    sm[t] = (i < n) ? deg[i] : 0;
    __syncthreads();
    for (int s = 512; s > 0; s >>= 1) {
        if (t < s) sm[t] += sm[t + s];
        __syncthreads();
    }
    if (t == 0) partials[blockIdx.x] = sm[0];
}

__global__ __launch_bounds__(64) void k_scan_base(int* __restrict__ partials, int nb,
                                                  int* __restrict__ offsets, int n) {
    __shared__ int sm[64];
    int t = threadIdx.x;
    int v = (t < nb) ? partials[t] : 0;
    sm[t] = v;
    __syncthreads();
    for (int off = 1; off < 64; off <<= 1) {
        int x = 0;
        if (t >= off) x = sm[t - off];
        __syncthreads();
        if (t >= off) sm[t] += x;
        __syncthreads();
    }
    if (t < nb) partials[t] = sm[t] - v;
    if (t == 63) offsets[n] = sm[63];
}

__global__ __launch_bounds__(1024) void k_scan_final(const int* __restrict__ deg,
                                                     const int* __restrict__ partials,
                                                     int* __restrict__ offsets,
                                                     int* __restrict__ cursor,
                                                     float* __restrict__ inv_deg, int n) {
    __shared__ int sm[1024];
    int t = threadIdx.x;
    int b = blockIdx.x;
    int i = b * 1024 + t;
    int v = (i < n) ? deg[i] : 0;
    sm[t] = v;
    __syncthreads();
    for (int off = 1; off < 1024; off <<= 1) {
        int x = 0;
        if (t >= off) x = sm[t - off];
        __syncthreads();
        if (t >= off) sm[t] += x;
        __syncthreads();
    }
    if (i < n) {
        int excl = partials[b] + sm[t] - v;
        offsets[i] = excl;
        cursor[i]  = excl;
        inv_deg[i] = 1.0f / fmaxf((float)v, 1.0f);
    }
}

__global__ void k_fill(const int* __restrict__ src, const int* __restrict__ dst,
                       int* __restrict__ cursor, int* __restrict__ csr, int e) {
    int i = blockIdx.x * blockDim.x + threadIdx.x;
    if (i < e) {
        int d = dst[i];
        int pos = atomicAdd(&cursor[d], 1);
        csr[pos] = src[i];
    }
}

// W fragment-major: per layer, fragment fc=(s*8+c): [fc][hl][lane][8] bf16.
// Fragment (s,c): col j = c*16 + (lane&15), k = s*32 + (lane>>4)*8 + jj.
// k<128 -> Wl[l][j][k] ; k>=128 -> Wr[l][j][k-128].
__global__ void k_wsplit(const float* __restrict__ Wl, const float* __restrict__ Wr,
                         unsigned short* __restrict__ Wf, int total) {
    int idx = blockIdx.x * blockDim.x + threadIdx.x;   // (l, s, c, lane)
    if (idx >= total) return;
    int l = idx >> 12;
    int rem = idx & 4095;
    int s = rem >> 9;
    int c = (rem >> 6) & 7;
    int lane = rem & 63;
    int j = c * 16 + (lane & 15);
    int k0 = s * 32 + (lane >> 4) * 8;
    size_t fc = (size_t)(idx >> 6);              // (l*8+s)*8+c
    size_t hbase = (fc * 2 * 64 + lane) * 8;     // [fc][hl=0][lane][8]
    size_t lbase = hbase + 512;                  // [fc][hl=1][lane][8]
    for (int jj = 0; jj < 8; ++jj) {
        int k = k0 + jj;
        float v;
        if (k < H) v = Wl[(size_t)l * H * H + j * H + k];
        else       v = Wr[(size_t)l * H * H + j * H + (k - H)];
        unsigned short hi = f2bf(v);
        unsigned short lo = f2bf(v - bf2f(hi));
        Wf[hbase + jj] = hi;
        Wf[lbase + jj] = lo;
    }
}

// ---------------- fused per-layer kernel ----------------
// Block = 256 threads = 4 waves, 64 rows = 4 tiles.
// Phase 1: 8 groups x 32 lanes gather-mean 8 nodes each (4-wide ILP),
//          split to bf16 hi/lo, store fragments to LDS (agg half, s=0..3).
// Phase 2: wave wv computes tile wv: s=0..3 A from LDS (ds_read_b128),
//          s=4..7 A = own h row loaded direct from global (128B/row contiguous,
//          L2-resident) and converted in-register. B from L2-hot Wf.
// LDS layout: AL[tile][s][hl][lane][8] ushort, tile<4, s<4 -> 32 KB.
__global__ __launch_bounds__(256) void k_fused(const float* __restrict__ h,
                                               const int* __restrict__ csr,
                                               const int* __restrict__ offsets,
                                               const float* __restrict__ inv_deg,
                                               const unsigned short* __restrict__ Wf,
                                               const float* __restrict__ bias,
                                               float* __restrict__ out, int n, int relu) {
    __shared__ unsigned short AL[16384];   // 32 KB

    int t = threadIdx.x;

    // ---- Phase 1: aggregate 64 nodes ----
    {
        int grp = t >> 5;      // 0..7
        int l4 = t & 31;
        const float4* hv = (const float4*)h;
        for (int i = 0; i < 8; ++i) {
            int bn = grp * 8 + i;                    // block-local node 0..63
            int gnode = blockIdx.x * 64 + bn;
            if (gnode >= n) break;                   // group-uniform
            int ps = offsets[gnode];
            int pe = offsets[gnode + 1];
            float4 a0 = make_float4(0.f, 0.f, 0.f, 0.f);
            float4 a1 = make_float4(0.f, 0.f, 0.f, 0.f);
            float4 a2 = make_float4(0.f, 0.f, 0.f, 0.f);
            float4 a3 = make_float4(0.f, 0.f, 0.f, 0.f);
            int p = ps;
            for (; p + 3 < pe; p += 4) {
                int i0 = csr[p], i1 = csr[p + 1], i2 = csr[p + 2], i3 = csr[p + 3];
                float4 v0 = hv[(size_t)i0 * 32 + l4];
                float4 v1 = hv[(size_t)i1 * 32 + l4];
                float4 v2 = hv[(size_t)i2 * 32 + l4];
                float4 v3 = hv[(size_t)i3 * 32 + l4];
                a0.x += v0.x; a0.y += v0.y; a0.z += v0.z; a0.w += v0.w;
                a1.x += v1.x; a1.y += v1.y; a1.z += v1.z; a1.w += v1.w;
                a2.x += v2.x; a2.y += v2.y; a2.z += v2.z; a2.w += v2.w;
                a3.x += v3.x; a3.y += v3.y; a3.z += v3.z; a3.w += v3.w;
            }
            for (; p < pe; ++p) {
                int i0 = csr[p];
                float4 v0 = hv[(size_t)i0 * 32 + l4];
                a0.x += v0.x; a0.y += v0.y; a0.z += v0.z; a0.w += v0.w;
            }
            float w = inv_deg[gnode];
            float4 acc;
            acc.x = ((a0.x + a1.x) + (a2.x + a3.x)) * w;
            acc.y = ((a0.y + a1.y) + (a2.y + a3.y)) * w;
            acc.z = ((a0.z + a1.z) + (a2.z + a3.z)) * w;
            acc.w = ((a0.w + a1.w) + (a2.w + a3.w)) * w;

            // fragment coords for this lane's 4 k-values (k = l4*4..+3)
            int tile = bn >> 4, r16 = bn & 15;
            int s = l4 >> 3;            // 0..3
            int kq = (l4 >> 1) & 3;
            int e0 = (l4 & 1) * 4;
            int offh = (((tile * 4 + s) * 2 + 0) * 64 + kq * 16 + r16) * 8 + e0;
            int offl = offh + 512;

            ushort4 hi4, lo4;
            hi4.x = f2bf(acc.x); lo4.x = f2bf(acc.x - bf2f(hi4.x));
            hi4.y = f2bf(acc.y); lo4.y = f2bf(acc.y - bf2f(hi4.y));
            hi4.z = f2bf(acc.z); lo4.z = f2bf(acc.z - bf2f(hi4.z));
            hi4.w = f2bf(acc.w); lo4.w = f2bf(acc.w - bf2f(hi4.w));
            *(ushort4*)(&AL[offh]) = hi4;
            *(ushort4*)(&AL[offl]) = lo4;
        }
    }
    __syncthreads();

    // ---- Phase 2: GEMM ----
    int wv = t >> 6;
    int lane = t & 63;
    int r16 = lane & 15;
    int kq = lane >> 4;
    int tile_g = blockIdx.x * 4 + wv;

    f32x4 acc[8];
#pragma unroll
    for (int c = 0; c < 8; ++c) acc[c] = (f32x4){0.f, 0.f, 0.f, 0.f};

    // s = 0..3: agg half from LDS
#pragma unroll
    for (int s = 0; s < 4; ++s) {
        int ab = (((wv * 4 + s) * 2) * 64 + lane) * 8;
        bf16x8 ah = *(const bf16x8*)(&AL[ab]);
        bf16x8 al = *(const bf16x8*)(&AL[ab + 512]);
#pragma unroll
        for (int c = 0; c < 8; ++c) {
            size_t wb = (((size_t)(s * 8 + c) * 2) * 64 + lane) * 8;
            bf16x8 b_hi = *(const bf16x8*)(Wf + wb);
            bf16x8 b_lo = *(const bf16x8*)(Wf + wb + 512);
            acc[c] = __builtin_amdgcn_mfma_f32_16x16x32_bf16(ah, b_hi, acc[c], 0, 0, 0);
            acc[c] = __builtin_amdgcn_mfma_f32_16x16x32_bf16(ah, b_lo, acc[c], 0, 0, 0);
            acc[c] = __builtin_amdgcn_mfma_f32_16x16x32_bf16(al, b_hi, acc[c], 0, 0, 0);
        }
    }

    // s = 4..7: root (h) half, direct global load + in-register split
    int grow = tile_g * 16 + r16;
    bool rok = grow < n;
#pragma unroll
    for (int s = 4; s < 8; ++s) {
        bf16x8 ah = {}, al = {};
        if (rok) {
            const float* hp = h + (size_t)grow * H + (s - 4) * 32 + kq * 8;
            float4 v0 = *(const float4*)hp;
            float4 v1 = *(const float4*)(hp + 4);
            unsigned short x;
            x = f2bf(v0.x); ah[0] = (short)x; al[0] = (short)f2bf(v0.x - bf2f(x));
            x = f2bf(v0.y); ah[1] = (short)x; al[1] = (short)f2bf(v0.y - bf2f(x));
            x = f2bf(v0.z); ah[2] = (short)x; al[2] = (short)f2bf(v0.z - bf2f(x));
            x = f2bf(v0.w); ah[3] = (short)x; al[3] = (short)f2bf(v0.w - bf2f(x));
            x = f2bf(v1.x); ah[4] = (short)x; al[4] = (short)f2bf(v1.x - bf2f(x));
            x = f2bf(v1.y); ah[5] = (short)x; al[5] = (short)f2bf(v1.y - bf2f(x));
            x = f2bf(v1.z); ah[6] = (short)x; al[6] = (short)f2bf(v1.z - bf2f(x));
            x = f2bf(v1.w); ah[7] = (short)x; al[7] = (short)f2bf(v1.w - bf2f(x));
        }
#pragma unroll
        for (int c = 0; c < 8; ++c) {
            size_t wb = (((size_t)(s * 8 + c) * 2) * 64 + lane) * 8;
            bf16x8 b_hi = *(const bf16x8*)(Wf + wb);
            bf16x8 b_lo = *(const bf16x8*)(Wf + wb + 512);
            acc[c] = __builtin_amdgcn_mfma_f32_16x16x32_bf16(ah, b_hi, acc[c], 0, 0, 0);
            acc[c] = __builtin_amdgcn_mfma_f32_16x16x32_bf16(ah, b_lo, acc[c], 0, 0, 0);
            acc[c] = __builtin_amdgcn_mfma_f32_16x16x32_bf16(al, b_hi, acc[c], 0, 0, 0);
        }
    }

    // epilogue
#pragma unroll
    for (int c = 0; c < 8; ++c) {
        int col = c * 16 + r16;
        float b = bias[col];
#pragma unroll
        for (int r = 0; r < 4; ++r) {
            int go = tile_g * 16 + kq * 4 + r;
            if (go < n) {
                float v = acc[c][r] + b;
                if (relu) v = fmaxf(v, 0.f);
                out[(size_t)go * H + col] = v;
            }
        }
    }
}

// ---------------- launch ----------------

extern "C" void kernel_launch(void* const* d_in, const int* in_sizes, int n_in,
                              void* d_out, int out_size, void* d_ws, size_t ws_size,
                              hipStream_t stream) {
    const float* x  = (const float*)d_in[0];
    const int*   ei = (const int*)d_in[1];
    const float* Wl = (const float*)d_in[2];
    const float* bl = (const float*)d_in[3];
    const float* Wr = (const float*)d_in[4];
    float* out = (float*)d_out;

    int n = in_sizes[0] / H;
    int e = in_sizes[1] / 2;
    const int* srcp = ei;
    const int* dstp = ei + e;

    char* w = (char*)d_ws;
    auto alloc = [&](size_t bytes) {
        char* p = w;
        w += (bytes + 255) & ~(size_t)255;
        return p;
    };
    int nb = (n + 1023) / 1024;
    int*            csr      = (int*)alloc((size_t)e * 4);
    int*            offsets  = (int*)alloc((size_t)(n + 1) * 4);
    int*            cursor   = (int*)alloc((size_t)n * 4);
    int*            deg      = (int*)alloc((size_t)n * 4);
    float*          inv_deg  = (float*)alloc((size_t)n * 4);
    int*            partials = (int*)alloc(64 * 4);
    unsigned short* Wf       = (unsigned short*)alloc((size_t)3 * 8 * 8 * 2 * 64 * 8 * 2);
    float*          hbuf     = (float*)alloc((size_t)n * H * 4);

    // CSR + inv_deg + W fragment-split (once per launch)
    k_zero_i32<<<(n + 255) / 256, 256, 0, stream>>>(deg, n);
    k_count<<<(e + 255) / 256, 256, 0, stream>>>(dstp, deg, e);
    k_scan_partial<<<nb, 1024, 0, stream>>>(deg, partials, n);
    k_scan_base<<<1, 64, 0, stream>>>(partials, nb, offsets, n);
    k_scan_final<<<nb, 1024, 0, stream>>>(deg, partials, offsets, cursor, inv_deg, n);
    k_fill<<<(e + 255) / 256, 256, 0, stream>>>(srcp, dstp, cursor, csr, e);
    int wtot = 3 * 8 * 8 * 64;
    k_wsplit<<<(wtot + 255) / 256, 256, 0, stream>>>(Wl, Wr, Wf, wtot);

    const float* hin[3]  = {x, out, hbuf};
    float*       hout[3] = {out, hbuf, out};
    int nblk = (n + 63) / 64;
    for (int l = 0; l < 3; ++l) {
        k_fused<<<nblk, 256, 0, stream>>>(hin[l], csr, offsets, inv_deg,
                                          Wf + (size_t)l * 8 * 8 * 2 * 64 * 8,
                                          bl + (size_t)l * H, hout[l], n, l < 2 ? 1 : 0);
    }
}

// Round 13
// 352.737 us; speedup vs baseline: 1.3749x; 1.3749x over previous
//
#include <hip/hip_runtime.h>
#include <hip/hip_bf16.h>

#define H 128

using bf16x8 = __attribute__((ext_vector_type(8))) short;
using f32x4  = __attribute__((ext_vector_type(4))) float;

__device__ inline unsigned short f2bf(float f) {
    unsigned u = __float_as_uint(f);
    unsigned r = (u + 0x7fffu + ((u >> 16) & 1u)) >> 16;
    return (unsigned short)r;
}
__device__ inline float bf2f(unsigned short b) {
    return __uint_as_float(((unsigned)b) << 16);
}

// ---------------- CSR build ----------------

__global__ void k_zero_i32(int* __restrict__ p, int n) {
    int i = blockIdx.x * blockDim.x + threadIdx.x;
    if (i < n) p[i] = 0;
}

__global__ void k_count(const int* __restrict__ dst, int* __restrict__ deg, int e) {
    int i = blockIdx.x * blockDim.x + threadIdx.x;
    if (i < e) atomicAdd(&deg[dst[i]], 1);
}

__global__ __launch_bounds__(1024) void k_scan_partial(const int* __restrict__ deg,
                                                       int* __restrict__ partials, int n) {
    __shared__ int sm[1024];
    int t = threadIdx.x;
    int i = blockIdx.x * 1024 + t;
    sm[t] = (i < n) ? deg[i] : 0;
    __syncthreads();
    for (int s = 512; s > 0; s >>= 1) {
        if (t < s) sm[t] += sm[t + s];
        __syncthreads();
    }
    if (t == 0) partials[blockIdx.x] = sm[0];
}

__global__ __launch_bounds__(64) void k_scan_base(int* __restrict__ partials, int nb,
                                                  int* __restrict__ offsets, int n) {
    __shared__ int sm[64];
    int t = threadIdx.x;
    int v = (t < nb) ? partials[t] : 0;
    sm[t] = v;
    __syncthreads();
    for (int off = 1; off < 64; off <<= 1) {
        int x = 0;
        if (t >= off) x = sm[t - off];
        __syncthreads();
        if (t >= off) sm[t] += x;
        __syncthreads();
    }
    if (t < nb) partials[t] = sm[t] - v;
    if (t == 63) offsets[n] = sm[63];
}

__global__ __launch_bounds__(1024) void k_scan_final(const int* __restrict__ deg,
                                                     const int* __restrict__ partials,
                                                     int* __restrict__ offsets,
                                                     int* __restrict__ cursor,
                                                     float* __restrict__ inv_deg, int n) {
    __shared__ int sm[1024];
    int t = threadIdx.x;
    int b = blockIdx.x;
    int i = b * 1024 + t;
    int v = (i < n) ? deg[i] : 0;
    sm[t] = v;
    __syncthreads();
    for (int off = 1; off < 1024; off <<= 1) {
        int x = 0;
        if (t >= off) x = sm[t - off];
        __syncthreads();
        if (t >= off) sm[t] += x;
        __syncthreads();
    }
    if (i < n) {
        int excl = partials[b] + sm[t] - v;
        offsets[i] = excl;
        cursor[i]  = excl;
        inv_deg[i] = 1.0f / fmaxf((float)v, 1.0f);
    }
}

__global__ void k_fill(const int* __restrict__ src, const int* __restrict__ dst,
                       int* __restrict__ cursor, int* __restrict__ csr, int e) {
    int i = blockIdx.x * blockDim.x + threadIdx.x;
    if (i < e) {
        int d = dst[i];
        int pos = atomicAdd(&cursor[d], 1);
        csr[pos] = src[i];
    }
}

// W fragment-major: per layer, fragment fc=(s*8+c): [fc][hl][lane][8] bf16.
// Fragment (s,c): col j = c*16 + (lane&15), k = s*32 + (lane>>4)*8 + jj.
// k<128 -> Wl[l][j][k] ; k>=128 -> Wr[l][j][k-128].
__global__ void k_wsplit(const float* __restrict__ Wl, const float* __restrict__ Wr,
                         unsigned short* __restrict__ Wf, int total) {
    int idx = blockIdx.x * blockDim.x + threadIdx.x;   // (l, s, c, lane)
    if (idx >= total) return;
    int l = idx >> 12;
    int rem = idx & 4095;
    int s = rem >> 9;
    int c = (rem >> 6) & 7;
    int lane = rem & 63;
    int j = c * 16 + (lane & 15);
    int k0 = s * 32 + (lane >> 4) * 8;
    size_t fc = (size_t)(idx >> 6);              // (l*8+s)*8+c
    size_t hbase = (fc * 2 * 64 + lane) * 8;     // [fc][hl=0][lane][8]
    size_t lbase = hbase + 512;                  // [fc][hl=1][lane][8]
    for (int jj = 0; jj < 8; ++jj) {
        int k = k0 + jj;
        float v;
        if (k < H) v = Wl[(size_t)l * H * H + j * H + k];
        else       v = Wr[(size_t)l * H * H + j * H + (k - H)];
        unsigned short hi = f2bf(v);
        unsigned short lo = f2bf(v - bf2f(hi));
        Wf[hbase + jj] = hi;
        Wf[lbase + jj] = lo;
    }
}

// ---------------- fused per-layer kernel ----------------
// Block = 256 threads = 4 waves, ONE 16-row tile per block (grid = n/16 = 3125:
// restores gather TLP lost in the 64-row version -> occupancy ceiling saturated).
// Phase 1: 8 groups x 32 lanes; each group aggregates 2 nodes serially,
//          splits to bf16 hi/lo, stores fragments to 8 KB LDS (agg half, s=0..3).
// Phase 2: wave wv computes col-fragments c = wv*2, wv*2+1 for the tile:
//          s=0..3 A from LDS (shared by all waves), s=4..7 A = h rows loaded
//          per-wave direct from global (L1/L2-hot) and split in-register.
// LDS: AL[s<4][hl<2][lane<64][8] ushort = 8 KB.
__global__ __launch_bounds__(256) void k_fused(const float* __restrict__ h,
                                               const int* __restrict__ csr,
                                               const int* __restrict__ offsets,
                                               const float* __restrict__ inv_deg,
                                               const unsigned short* __restrict__ Wf,
                                               const float* __restrict__ bias,
                                               float* __restrict__ out, int n, int relu) {
    __shared__ unsigned short AL[4096];   // 8 KB

    int t = threadIdx.x;

    // ---- Phase 1: aggregate 16 nodes (2 per 32-lane group) ----
    {
        int grp = t >> 5;      // 0..7
        int l4 = t & 31;
        const float4* hv = (const float4*)h;
#pragma unroll
        for (int i = 0; i < 2; ++i) {
            int bn = grp * 2 + i;                    // block-local node 0..15
            int gnode = blockIdx.x * 16 + bn;
            if (gnode >= n) break;                   // group-uniform
            int ps = offsets[gnode];
            int pe = offsets[gnode + 1];
            float4 a0 = make_float4(0.f, 0.f, 0.f, 0.f);
            float4 a1 = make_float4(0.f, 0.f, 0.f, 0.f);
            float4 a2 = make_float4(0.f, 0.f, 0.f, 0.f);
            float4 a3 = make_float4(0.f, 0.f, 0.f, 0.f);
            int p = ps;
            for (; p + 3 < pe; p += 4) {
                int i0 = csr[p], i1 = csr[p + 1], i2 = csr[p + 2], i3 = csr[p + 3];
                float4 v0 = hv[(size_t)i0 * 32 + l4];
                float4 v1 = hv[(size_t)i1 * 32 + l4];
                float4 v2 = hv[(size_t)i2 * 32 + l4];
                float4 v3 = hv[(size_t)i3 * 32 + l4];
                a0.x += v0.x; a0.y += v0.y; a0.z += v0.z; a0.w += v0.w;
                a1.x += v1.x; a1.y += v1.y; a1.z += v1.z; a1.w += v1.w;
                a2.x += v2.x; a2.y += v2.y; a2.z += v2.z; a2.w += v2.w;
                a3.x += v3.x; a3.y += v3.y; a3.z += v3.z; a3.w += v3.w;
            }
            for (; p < pe; ++p) {
                int i0 = csr[p];
                float4 v0 = hv[(size_t)i0 * 32 + l4];
                a0.x += v0.x; a0.y += v0.y; a0.z += v0.z; a0.w += v0.w;
            }
            float w = inv_deg[gnode];
            float4 acc;
            acc.x = ((a0.x + a1.x) + (a2.x + a3.x)) * w;
            acc.y = ((a0.y + a1.y) + (a2.y + a3.y)) * w;
            acc.z = ((a0.z + a1.z) + (a2.z + a3.z)) * w;
            acc.w = ((a0.w + a1.w) + (a2.w + a3.w)) * w;

            // fragment coords for this lane's 4 k-values (k = l4*4..+3)
            int r16 = bn;               // 0..15
            int s = l4 >> 3;            // 0..3
            int kq = (l4 >> 1) & 3;
            int e0 = (l4 & 1) * 4;
            int offh = ((s * 2 + 0) * 64 + kq * 16 + r16) * 8 + e0;
            int offl = offh + 512;

            ushort4 hi4, lo4;
            hi4.x = f2bf(acc.x); lo4.x = f2bf(acc.x - bf2f(hi4.x));
            hi4.y = f2bf(acc.y); lo4.y = f2bf(acc.y - bf2f(hi4.y));
            hi4.z = f2bf(acc.z); lo4.z = f2bf(acc.z - bf2f(hi4.z));
            hi4.w = f2bf(acc.w); lo4.w = f2bf(acc.w - bf2f(hi4.w));
            *(ushort4*)(&AL[offh]) = hi4;
            *(ushort4*)(&AL[offl]) = lo4;
        }
    }
    __syncthreads();

    // ---- Phase 2: GEMM (wave wv owns col-fragments wv*2 and wv*2+1) ----
    int wv = t >> 6;
    int lane = t & 63;
    int r16 = lane & 15;
    int kq = lane >> 4;

    f32x4 acc[2];
    acc[0] = (f32x4){0.f, 0.f, 0.f, 0.f};
    acc[1] = (f32x4){0.f, 0.f, 0.f, 0.f};

    // s = 0..3: agg half from LDS
#pragma unroll
    for (int s = 0; s < 4; ++s) {
        int ab = ((s * 2) * 64 + lane) * 8;
        bf16x8 ah = *(const bf16x8*)(&AL[ab]);
        bf16x8 al = *(const bf16x8*)(&AL[ab + 512]);
#pragma unroll
        for (int j = 0; j < 2; ++j) {
            int c = wv * 2 + j;
            size_t wb = (((size_t)(s * 8 + c) * 2) * 64 + lane) * 8;
            bf16x8 b_hi = *(const bf16x8*)(Wf + wb);
            bf16x8 b_lo = *(const bf16x8*)(Wf + wb + 512);
            acc[j] = __builtin_amdgcn_mfma_f32_16x16x32_bf16(ah, b_hi, acc[j], 0, 0, 0);
            acc[j] = __builtin_amdgcn_mfma_f32_16x16x32_bf16(ah, b_lo, acc[j], 0, 0, 0);
            acc[j] = __builtin_amdgcn_mfma_f32_16x16x32_bf16(al, b_hi, acc[j], 0, 0, 0);
        }
    }

    // s = 4..7: root (h) half, direct global load + in-register split
    int grow = blockIdx.x * 16 + r16;
    bool rok = grow < n;
#pragma unroll
    for (int s = 4; s < 8; ++s) {
        bf16x8 ah = {}, al = {};
        if (rok) {
            const float* hp = h + (size_t)grow * H + (s - 4) * 32 + kq * 8;
            float4 v0 = *(const float4*)hp;
            float4 v1 = *(const float4*)(hp + 4);
            unsigned short x;
            x = f2bf(v0.x); ah[0] = (short)x; al[0] = (short)f2bf(v0.x - bf2f(x));
            x = f2bf(v0.y); ah[1] = (short)x; al[1] = (short)f2bf(v0.y - bf2f(x));
            x = f2bf(v0.z); ah[2] = (short)x; al[2] = (short)f2bf(v0.z - bf2f(x));
            x = f2bf(v0.w); ah[3] = (short)x; al[3] = (short)f2bf(v0.w - bf2f(x));
            x = f2bf(v1.x); ah[4] = (short)x; al[4] = (short)f2bf(v1.x - bf2f(x));
            x = f2bf(v1.y); ah[5] = (short)x; al[5] = (short)f2bf(v1.y - bf2f(x));
            x = f2bf(v1.z); ah[6] = (short)x; al[6] = (short)f2bf(v1.z - bf2f(x));
            x = f2bf(v1.w); ah[7] = (short)x; al[7] = (short)f2bf(v1.w - bf2f(x));
        }
#pragma unroll
        for (int j = 0; j < 2; ++j) {
            int c = wv * 2 + j;
            size_t wb = (((size_t)(s * 8 + c) * 2) * 64 + lane) * 8;
            bf16x8 b_hi = *(const bf16x8*)(Wf + wb);
            bf16x8 b_lo = *(const bf16x8*)(Wf + wb + 512);
            acc[j] = __builtin_amdgcn_mfma_f32_16x16x32_bf16(ah, b_hi, acc[j], 0, 0, 0);
            acc[j] = __builtin_amdgcn_mfma_f32_16x16x32_bf16(ah, b_lo, acc[j], 0, 0, 0);
            acc[j] = __builtin_amdgcn_mfma_f32_16x16x32_bf16(al, b_hi, acc[j], 0, 0, 0);
        }
    }

    // epilogue: wave wv writes cols [wv*32, wv*32+31] for the 16 rows
#pragma unroll
    for (int j = 0; j < 2; ++j) {
        int col = (wv * 2 + j) * 16 + r16;
        float b = bias[col];
#pragma unroll
        for (int r = 0; r < 4; ++r) {
            int go = blockIdx.x * 16 + kq * 4 + r;
            if (go < n) {
                float v = acc[j][r] + b;
                if (relu) v = fmaxf(v, 0.f);
                out[(size_t)go * H + col] = v;
            }
        }
    }
}

// ---------------- launch ----------------

extern "C" void kernel_launch(void* const* d_in, const int* in_sizes, int n_in,
                              void* d_out, int out_size, void* d_ws, size_t ws_size,
                              hipStream_t stream) {
    const float* x  = (const float*)d_in[0];
    const int*   ei = (const int*)d_in[1];
    const float* Wl = (const float*)d_in[2];
    const float* bl = (const float*)d_in[3];
    const float* Wr = (const float*)d_in[4];
    float* out = (float*)d_out;

    int n = in_sizes[0] / H;
    int e = in_sizes[1] / 2;
    const int* srcp = ei;
    const int* dstp = ei + e;

    char* w = (char*)d_ws;
    auto alloc = [&](size_t bytes) {
        char* p = w;
        w += (bytes + 255) & ~(size_t)255;
        return p;
    };
    int nb = (n + 1023) / 1024;
    int*            csr      = (int*)alloc((size_t)e * 4);
    int*            offsets  = (int*)alloc((size_t)(n + 1) * 4);
    int*            cursor   = (int*)alloc((size_t)n * 4);
    int*            deg      = (int*)alloc((size_t)n * 4);
    float*          inv_deg  = (float*)alloc((size_t)n * 4);
    int*            partials = (int*)alloc(64 * 4);
    unsigned short* Wf       = (unsigned short*)alloc((size_t)3 * 8 * 8 * 2 * 64 * 8 * 2);
    float*          hbuf     = (float*)alloc((size_t)n * H * 4);

    // CSR + inv_deg + W fragment-split (once per launch)
    k_zero_i32<<<(n + 255) / 256, 256, 0, stream>>>(deg, n);
    k_count<<<(e + 255) / 256, 256, 0, stream>>>(dstp, deg, e);
    k_scan_partial<<<nb, 1024, 0, stream>>>(deg, partials, n);
    k_scan_base<<<1, 64, 0, stream>>>(partials, nb, offsets, n);
    k_scan_final<<<nb, 1024, 0, stream>>>(deg, partials, offsets, cursor, inv_deg, n);
    k_fill<<<(e + 255) / 256, 256, 0, stream>>>(srcp, dstp, cursor, csr, e);
    int wtot = 3 * 8 * 8 * 64;
    k_wsplit<<<(wtot + 255) / 256, 256, 0, stream>>>(Wl, Wr, Wf, wtot);

    const float* hin[3]  = {x, out, hbuf};
    float*       hout[3] = {out, hbuf, out};
    int nblk = (n + 15) / 16;
    for (int l = 0; l < 3; ++l) {
        k_fused<<<nblk, 256, 0, stream>>>(hin[l], csr, offsets, inv_deg,
                                          Wf + (size_t)l * 8 * 8 * 2 * 64 * 8,
                                          bl + (size_t)l * H, hout[l], n, l < 2 ? 1 : 0);
    }
}